// Round 7
// baseline (2777.217 us; speedup 1.0000x reference)
//
#include <hip/hip_runtime.h>

#define T_LEN 386
#define NSPAN 73920

typedef float v4f __attribute__((ext_vector_type(4)));

// ---- XCD-L2 ops (sc0: bypass L1, hit the shared per-XCD L2) ----
__device__ inline void l2_load8(const float* p, v4f& a, v4f& b) {
    asm volatile("global_load_dwordx4 %0, %2, off sc0\n\t"
                 "global_load_dwordx4 %1, %2, off offset:16 sc0\n\t"
                 "s_waitcnt vmcnt(0)"
                 : "=&v"(a), "=&v"(b) : "v"(p) : "memory");
}
__device__ inline void l2_store1(float* p, float v) {
    asm volatile("global_store_dword %0, %1, off sc0"
                 :: "v"(p), "v"(v) : "memory");
}
// ---- LLC ops (sc0 sc1: device scope, cross-XCD safe) ----
__device__ inline void llc_load8(const float* p, v4f& a, v4f& b) {
    asm volatile("global_load_dwordx4 %0, %2, off sc0 sc1\n\t"
                 "global_load_dwordx4 %1, %2, off offset:16 sc0 sc1\n\t"
                 "s_waitcnt vmcnt(0)"
                 : "=&v"(a), "=&v"(b) : "v"(p) : "memory");
}
__device__ inline void llc_store1(float* p, float v) {
    asm volatile("global_store_dword %0, %1, off sc0 sc1"
                 :: "v"(p), "v"(v) : "memory");
}

__device__ inline int get_xcc_id() {
    int x;
    asm volatile("s_getreg_b32 %0, hwreg(HW_REG_XCC_ID)" : "=s"(x));
    return x & 7;
}

__device__ inline float fsigmoid(float x) { return 1.f / (1.f + __expf(-x)); }
__device__ inline float ftanh(float x) {
    x = fminf(fmaxf(x, -15.f), 15.f);
    float e = __expf(2.f * x);
    return (e - 1.f) / (e + 1.f);
}

// ---------------- kernel 1: embedding concat ----------------
__global__ void k_embed(const int* __restrict__ tag_ids, const int* __restrict__ word_ids,
                        const float* __restrict__ tag_emb, const float* __restrict__ word_emb,
                        float* __restrict__ x) {
    int t = blockIdx.x;
    int tid = threadIdx.x; // 128
    int tr = tag_ids[t], wr = word_ids[t];
    x[t * 512 + tid] = tag_emb[tr * 128 + tid];
    for (int j = tid; j < 384; j += 128)
        x[t * 512 + 128 + j] = word_emb[wr * 384 + j];
}

// ---------------- kernel 2: gx = x(rev) @ Wih^T + b ----------------
__global__ void k_gx(const float* __restrict__ x,
                     const float* __restrict__ Wf, const float* __restrict__ bf,
                     const float* __restrict__ Wb, const float* __restrict__ bb,
                     float* __restrict__ gxf, float* __restrict__ gxb) {
    __shared__ float xs[32 * 512];
    int dir = blockIdx.z;
    const float* W = dir ? Wb : Wf;
    const float* bias = dir ? bb : bf;
    float* out = dir ? gxb : gxf;
    int nbase = blockIdx.x * 64;
    int tbase = blockIdx.y * 32;
    int tid = threadIdx.x;

    for (int i = tid; i < 32 * 128; i += 256) {
        int row = i >> 7, c4 = i & 127;
        int t = tbase + row;
        float4 v = make_float4(0.f, 0.f, 0.f, 0.f);
        if (t < T_LEN) {
            int src = dir ? (T_LEN - 1 - t) : t;
            v = ((const float4*)(x + src * 512))[c4];
        }
        ((float4*)xs)[i] = v;
    }
    __syncthreads();

    int col = tid >> 2;
    int kq = tid & 3;
    int n = nbase + col;
    const float4* wrow = (const float4*)(W + (long)n * 512);
    float acc[32];
#pragma unroll
    for (int r = 0; r < 32; ++r) acc[r] = 0.f;
#pragma unroll 2
    for (int it = 0; it < 32; ++it) {
        int k4 = it * 4 + kq;
        float4 w = wrow[k4];
#pragma unroll
        for (int r = 0; r < 32; ++r) {
            float4 xv = ((const float4*)(xs + r * 512))[k4];
            acc[r] += w.x * xv.x + w.y * xv.y + w.z * xv.z + w.w * xv.w;
        }
    }
#pragma unroll
    for (int r = 0; r < 32; ++r) {
        float v = acc[r];
        v += __shfl_xor(v, 1, 4);
        v += __shfl_xor(v, 2, 4);
        acc[r] = v;
    }
    if (kq == 0) {
        float bv = bias[n];
        for (int r = 0; r < 32; ++r) {
            int t = tbase + r;
            if (t < T_LEN) out[t * 2048 + n] = acc[r] + bv;
        }
    }
}

// ---------------- kernel 2b: poison fwd/bwd (+mirrors) with sentinel 2.0f ----------------
__global__ void k_poison(float* __restrict__ st) {
    int i = blockIdx.x * 256 + threadIdx.x;
    __hip_atomic_store(st + i, 2.0f, __ATOMIC_RELAXED, __HIP_MEMORY_SCOPE_AGENT);
}

// ---------------- kernel 3a: XCD-elected persistent scan (cooperative, 256 blocks) ----------------
// Each block reads its real XCD id (s_getreg HW_REG_XCC_ID), registers in
// ectrl[xcd], waits for all 256, then the first two XCDs with >=32 blocks
// provide the 32 dir-0 / 32 dir-1 workers. Worker h-exchange: sc0 store +
// sc0 poll through the SHARED per-XCD L2 (~200cy RT). LLC mirror (sc0 sc1)
// written too; consumers fall back to it after 24 fast misses -> correct
// under any placement. Non-workers exit.
__launch_bounds__(256, 1)
__global__ void k_scan_xcd(const float* __restrict__ gxf, const float* __restrict__ gxb,
                           const float* __restrict__ Wfhh, const float* __restrict__ Wbhh,
                           float* fwd, float* bwd, float* fwdm, float* bwdm,
                           int* ectrl) {
    __shared__ float gx_sh[T_LEN * 64];
    __shared__ float h_sh[2][512];
    __shared__ int sh_role;
    int tid = threadIdx.x;

    if (tid == 0) {
        int xcc = get_xcc_id();
        int slot = __hip_atomic_fetch_add(&ectrl[xcc], 1, __ATOMIC_RELAXED,
                                          __HIP_MEMORY_SCOPE_AGENT);
        int total;
        do {
            total = 0;
            for (int i = 0; i < 8; ++i)
                total += __hip_atomic_load(&ectrl[i], __ATOMIC_RELAXED,
                                           __HIP_MEMORY_SCOPE_AGENT);
        } while (total < (int)gridDim.x);
        int xa = -1, xb = -1;
        for (int i = 0; i < 8; ++i) {
            int ci = __hip_atomic_load(&ectrl[i], __ATOMIC_RELAXED,
                                       __HIP_MEMORY_SCOPE_AGENT);
            if (ci >= 32) { if (xa < 0) xa = i; else if (xb < 0) xb = i; }
        }
        int role = -1;
        if (xa >= 0 && xb >= 0) {
            if (xcc == xa && slot < 32) role = slot;            // dir 0
            else if (xcc == xb && slot < 32) role = 32 + slot;  // dir 1
        } else {
            if (blockIdx.x < 64) role = blockIdx.x;             // degenerate fallback
        }
        sh_role = role;
    }
    __syncthreads();
    int role = sh_role;
    if (role < 0) return;
    int dir = role >> 5;
    int w = role & 31;

    const float* gx = dir ? gxb : gxf;
    const float* Whh = dir ? Wbhh : Wfhh;
    float* st  = dir ? bwd  : fwd;
    float* stm = dir ? bwdm : fwdm;

    for (int idx = tid; idx < T_LEN * 64; idx += 256) {
        int t = idx >> 6, j = idx & 63;
        gx_sh[idx] = gx[t * 2048 + (j >> 4) * 512 + w * 16 + (j & 15)];
    }

    int u = tid >> 4;
    int r = tid & 15;
    int g = r >> 2;
    int kq = r & 3;
    int grow = g * 512 + w * 16 + u;
    float4 wreg[32];
    const float4* wsrc = (const float4*)(Whh + (long)grow * 512);
#pragma unroll
    for (int it = 0; it < 32; ++it) wreg[it] = wsrc[it * 4 + kq];
    float c = 0.f;
    __syncthreads();

    for (int ts = 0; ts < T_LEN; ++ts) {
        float* hbuf = h_sh[ts & 1];
        if (tid < 64) {
            if (ts == 0) {
                float4 z = make_float4(0.f, 0.f, 0.f, 0.f);
                *(float4*)(hbuf + tid * 8) = z;
                *(float4*)(hbuf + tid * 8 + 4) = z;
            } else {
                int srow = dir ? (T_LEN - ts) : (ts - 1);
                const float* src  = st  + srow * 512 + tid * 8;
                const float* srcm = stm + srow * 512 + tid * 8;
                v4f a, b;
                int tries = 0;
                for (;;) {
                    l2_load8(src, a, b);
                    bool bad = a.x == 2.f || a.y == 2.f || a.z == 2.f || a.w == 2.f ||
                               b.x == 2.f || b.y == 2.f || b.z == 2.f || b.w == 2.f;
                    if (!bad) break;
                    if (++tries > 24) {
                        llc_load8(srcm, a, b);
                        bad = a.x == 2.f || a.y == 2.f || a.z == 2.f || a.w == 2.f ||
                              b.x == 2.f || b.y == 2.f || b.z == 2.f || b.w == 2.f;
                        if (!bad) break;
                    }
                }
                *(v4f*)(hbuf + tid * 8) = a;
                *(v4f*)(hbuf + tid * 8 + 4) = b;
            }
        }
        __syncthreads();

        const float4* hv = (const float4*)hbuf;
        float a0 = 0.f, a1 = 0.f, a2 = 0.f, a3 = 0.f;
#pragma unroll
        for (int it = 0; it < 32; ++it) {
            float4 h4 = hv[it * 4 + kq];
            float4 w4 = wreg[it];
            a0 += w4.x * h4.x; a1 += w4.y * h4.y;
            a2 += w4.z * h4.z; a3 += w4.w * h4.w;
        }
        float v = (a0 + a1) + (a2 + a3);
        v += __shfl_xor(v, 1, 4);
        v += __shfl_xor(v, 2, 4);
        float gi = __shfl(v, (u & 3) * 16 + 0, 64)  + gx_sh[ts * 64 + u];
        float gf = __shfl(v, (u & 3) * 16 + 4, 64)  + gx_sh[ts * 64 + 16 + u];
        float gg = __shfl(v, (u & 3) * 16 + 8, 64)  + gx_sh[ts * 64 + 32 + u];
        float go = __shfl(v, (u & 3) * 16 + 12, 64) + gx_sh[ts * 64 + 48 + u];
        float i_ = fsigmoid(gi);
        float f_ = fsigmoid(gf);
        float o_ = fsigmoid(go);
        c = f_ * c + i_ * ftanh(gg);
        float h = o_ * ftanh(c);
        if (r == 0) {
            int drow = dir ? (T_LEN - 1 - ts) : ts;
            l2_store1(st + drow * 512 + w * 16 + u, h);     // XCD-L2 fast path
            llc_store1(stm + drow * 512 + w * 16 + u, h);   // LLC mirror
        }
    }
}

// ---------------- kernel 3b: proven LLC-only scan (fallback if coop launch fails) ----------------
__launch_bounds__(256, 1)
__global__ void k_scan(const float* __restrict__ gxf, const float* __restrict__ gxb,
                       const float* __restrict__ Wfhh, const float* __restrict__ Wbhh,
                       float* fwd, float* bwd) {
    __shared__ float gx_sh[T_LEN * 64];
    __shared__ float h_sh[2][512];
    int bid = blockIdx.x;
    int dir = bid >> 5;
    int w = bid & 31;
    int tid = threadIdx.x;
    const float* gx = dir ? gxb : gxf;
    const float* Whh = dir ? Wbhh : Wfhh;
    float* st = dir ? bwd : fwd;

    for (int idx = tid; idx < T_LEN * 64; idx += 256) {
        int t = idx >> 6, j = idx & 63;
        gx_sh[idx] = gx[t * 2048 + (j >> 4) * 512 + w * 16 + (j & 15)];
    }

    int u = tid >> 4;
    int r = tid & 15;
    int g = r >> 2;
    int kq = r & 3;
    int grow = g * 512 + w * 16 + u;
    float4 wreg[32];
    const float4* wsrc = (const float4*)(Whh + (long)grow * 512);
#pragma unroll
    for (int it = 0; it < 32; ++it) wreg[it] = wsrc[it * 4 + kq];
    float c = 0.f;

    for (int ts = 0; ts < T_LEN; ++ts) {
        float* hbuf = h_sh[ts & 1];
        if (tid < 64) {
            if (ts == 0) {
                float4 z = make_float4(0.f, 0.f, 0.f, 0.f);
                *(float4*)(hbuf + tid * 8) = z;
                *(float4*)(hbuf + tid * 8 + 4) = z;
            } else {
                int srow = dir ? (T_LEN - ts) : (ts - 1);
                const float* src = st + srow * 512 + tid * 8;
                v4f a, b;
                for (;;) {
                    llc_load8(src, a, b);
                    bool bad = a.x == 2.f || a.y == 2.f || a.z == 2.f || a.w == 2.f ||
                               b.x == 2.f || b.y == 2.f || b.z == 2.f || b.w == 2.f;
                    if (!bad) break;
                }
                *(v4f*)(hbuf + tid * 8) = a;
                *(v4f*)(hbuf + tid * 8 + 4) = b;
            }
        }
        __syncthreads();

        const float4* hv = (const float4*)hbuf;
        float a0 = 0.f, a1 = 0.f, a2 = 0.f, a3 = 0.f;
#pragma unroll
        for (int it = 0; it < 32; ++it) {
            float4 h4 = hv[it * 4 + kq];
            float4 w4 = wreg[it];
            a0 += w4.x * h4.x; a1 += w4.y * h4.y;
            a2 += w4.z * h4.z; a3 += w4.w * h4.w;
        }
        float v = (a0 + a1) + (a2 + a3);
        v += __shfl_xor(v, 1, 4);
        v += __shfl_xor(v, 2, 4);
        float gi = __shfl(v, (u & 3) * 16 + 0, 64)  + gx_sh[ts * 64 + u];
        float gf = __shfl(v, (u & 3) * 16 + 4, 64)  + gx_sh[ts * 64 + 16 + u];
        float gg = __shfl(v, (u & 3) * 16 + 8, 64)  + gx_sh[ts * 64 + 32 + u];
        float go = __shfl(v, (u & 3) * 16 + 12, 64) + gx_sh[ts * 64 + 48 + u];
        float i_ = fsigmoid(gi);
        float f_ = fsigmoid(gf);
        float o_ = fsigmoid(go);
        c = f_ * c + i_ * ftanh(gg);
        float h = o_ * ftanh(c);
        if (r == 0) {
            int drow = dir ? (T_LEN - 1 - ts) : ts;
            llc_store1(st + drow * 512 + w * 16 + u, h);
        }
    }
}

// ---------------- kernel 4: position tables ----------------
__global__ void k_tables(const float* __restrict__ fwd, const float* __restrict__ bwd,
                         const float* __restrict__ W1, const float* __restrict__ V1,
                         float* __restrict__ A, float* __restrict__ B,
                         float* __restrict__ AV, float* __restrict__ BV) {
    __shared__ float xs[32 * 512];
    int which = blockIdx.z;
    const float* S = (which & 1) ? bwd : fwd;
    const float* W = ((which >> 1) ? V1 : W1) + (which & 1) * 512 * 1024;
    float* out = which == 0 ? A : which == 1 ? B : which == 2 ? AV : BV;
    int nbase = blockIdx.x * 64, tbase = blockIdx.y * 32;
    int tid = threadIdx.x;

    for (int i = tid; i < 32 * 128; i += 256) {
        int row = i >> 7, c4 = i & 127;
        int t = tbase + row;
        float4 v = make_float4(0.f, 0.f, 0.f, 0.f);
        if (t < T_LEN) v = ((const float4*)(S + t * 512))[c4];
        ((float4*)xs)[i] = v;
    }
    __syncthreads();

    int cg = tid & 15;
    int rg = tid >> 4;
    int n = nbase + cg * 4;
    float4 acc0 = make_float4(0.f, 0.f, 0.f, 0.f);
    float4 acc1 = make_float4(0.f, 0.f, 0.f, 0.f);
#pragma unroll 4
    for (int k = 0; k < 512; ++k) {
        float4 wv = *(const float4*)(W + (long)k * 1024 + n);
        float x0 = xs[(rg * 2) * 512 + k];
        float x1 = xs[(rg * 2 + 1) * 512 + k];
        acc0.x += x0 * wv.x; acc0.y += x0 * wv.y; acc0.z += x0 * wv.z; acc0.w += x0 * wv.w;
        acc1.x += x1 * wv.x; acc1.y += x1 * wv.y; acc1.z += x1 * wv.z; acc1.w += x1 * wv.w;
    }
    int t0 = tbase + rg * 2, t1 = t0 + 1;
    if (t0 < T_LEN) *(float4*)(out + (long)t0 * 1024 + n) = acc0;
    if (t1 < T_LEN) *(float4*)(out + (long)t1 * 1024 + n) = acc1;
}

// ---------------- kernel 5: fused span FFN ----------------
#define TS 64
#define KC 32
__launch_bounds__(256, 4)
__global__ void k_span(const float* __restrict__ A, const float* __restrict__ B,
                       const float* __restrict__ AV, const float* __restrict__ BV,
                       const float* __restrict__ W2, const float* __restrict__ b1,
                       const float* __restrict__ b2, const float* __restrict__ V2,
                       const float* __restrict__ c1, const float* __restrict__ c2,
                       float* __restrict__ out) {
    __shared__ float hid[TS][KC + 4];
    __shared__ float w2s[KC * 128];
    __shared__ int ls[TS], rs[TS];
    int tid = threadIdx.x;
    int wg = blockIdx.x;

    if (tid < TS) {
        int s = wg * TS + tid;
        float disc = 769.0f * 769.0f - 8.0f * (float)s;
        int l = (int)floorf((769.0f - sqrtf(disc)) * 0.5f);
        if (l < 0) l = 0;
        if (l > 383) l = 383;
#define OFF(L) ((L) * 384 - ((L) * ((L) - 1)) / 2)
        while (l + 1 <= 384 && OFF(l + 1) <= s) ++l;
        while (l > 0 && OFF(l) > s) --l;
        int r = l + 1 + (s - OFF(l));
        ls[tid] = l; rs[tid] = r;
    }
    float acc[8][4];
#pragma unroll
    for (int a = 0; a < 8; ++a)
#pragma unroll
        for (int b = 0; b < 4; ++b) acc[a][b] = 0.f;
    float vacc[2] = {0.f, 0.f};
    int chg = tid & 31, sgm = tid >> 5;
    int kq = tid & 7, sgb = tid >> 3;
    __syncthreads();

    for (int kb = 0; kb < 1024; kb += KC) {
        if (kb) __syncthreads();
        for (int i = tid; i < KC * 128 / 4; i += 256)
            ((float4*)w2s)[i] = ((const float4*)(W2 + kb * 128))[i];
        int ko = kb + kq * 4;
        float4 bv = *(const float4*)(b1 + ko);
        float4 cv = *(const float4*)(c1 + ko);
        float4 v2 = *(const float4*)(V2 + ko);
#pragma unroll
        for (int si = 0; si < 2; ++si) {
            int sp = sgb * 2 + si;
            int l = ls[sp], r = rs[sp];
            float4 ar = *(const float4*)(A + (long)r * 1024 + ko);
            float4 al = *(const float4*)(A + (long)l * 1024 + ko);
            float4 bl = *(const float4*)(B + (long)(l + 1) * 1024 + ko);
            float4 br = *(const float4*)(B + (long)(r + 1) * 1024 + ko);
            float4 hx;
            hx.x = fmaxf(ar.x - al.x + bl.x - br.x + bv.x, 0.f);
            hx.y = fmaxf(ar.y - al.y + bl.y - br.y + bv.y, 0.f);
            hx.z = fmaxf(ar.z - al.z + bl.z - br.z + bv.z, 0.f);
            hx.w = fmaxf(ar.w - al.w + bl.w - br.w + bv.w, 0.f);
            *(float4*)&hid[sp][kq * 4] = hx;
            float4 vr = *(const float4*)(AV + (long)r * 1024 + ko);
            float4 vl = *(const float4*)(AV + (long)l * 1024 + ko);
            float4 ul = *(const float4*)(BV + (long)(l + 1) * 1024 + ko);
            float4 ur = *(const float4*)(BV + (long)(r + 1) * 1024 + ko);
            float h0 = fmaxf(vr.x - vl.x + ul.x - ur.x + cv.x, 0.f);
            float h1 = fmaxf(vr.y - vl.y + ul.y - ur.y + cv.y, 0.f);
            float h2 = fmaxf(vr.z - vl.z + ul.z - ur.z + cv.z, 0.f);
            float h3 = fmaxf(vr.w - vl.w + ul.w - ur.w + cv.w, 0.f);
            vacc[si] += h0 * v2.x + h1 * v2.y + h2 * v2.z + h3 * v2.w;
        }
        __syncthreads();
#pragma unroll 2
        for (int k = 0; k < KC; k += 4) {
            float4 h4[8];
#pragma unroll
            for (int j2 = 0; j2 < 8; ++j2)
                h4[j2] = *(const float4*)&hid[sgm * 8 + j2][k];
#pragma unroll
            for (int kk = 0; kk < 4; ++kk) {
                float4 wv = *(const float4*)&w2s[(k + kk) * 128 + chg * 4];
#pragma unroll
                for (int j2 = 0; j2 < 8; ++j2) {
                    float hx = (&h4[j2].x)[kk];
                    acc[j2][0] += hx * wv.x; acc[j2][1] += hx * wv.y;
                    acc[j2][2] += hx * wv.z; acc[j2][3] += hx * wv.w;
                }
            }
        }
    }

    float4 b2v = *(const float4*)(b2 + chg * 4);
#pragma unroll
    for (int j2 = 0; j2 < 8; ++j2) {
        int s = wg * TS + sgm * 8 + j2;
        float* o = out + (long)s * 129 + chg * 4;
        o[0] = acc[j2][0] + b2v.x; o[1] = acc[j2][1] + b2v.y;
        o[2] = acc[j2][2] + b2v.z; o[3] = acc[j2][3] + b2v.w;
    }
    float c2v = c2[0];
#pragma unroll
    for (int si = 0; si < 2; ++si) {
        float v = vacc[si];
        v += __shfl_xor(v, 4, 8);
        v += __shfl_xor(v, 2, 8);
        v += __shfl_xor(v, 1, 8);
        if (kq == 0) out[(long)(wg * TS + sgb * 2 + si) * 129 + 128] = v + c2v;
    }
}

extern "C" void kernel_launch(void* const* d_in, const int* in_sizes, int n_in,
                              void* d_out, int out_size, void* d_ws, size_t ws_size,
                              hipStream_t stream) {
    const int* tag_ids  = (const int*)d_in[0];
    const int* word_ids = (const int*)d_in[1];
    const float* tag_emb  = (const float*)d_in[2];
    const float* word_emb = (const float*)d_in[3];
    const float* Wf_ih = (const float*)d_in[4];
    const float* Wf_hh = (const float*)d_in[5];
    const float* bf    = (const float*)d_in[6];
    const float* Wb_ih = (const float*)d_in[7];
    const float* Wb_hh = (const float*)d_in[8];
    const float* bb    = (const float*)d_in[9];
    const float* W1 = (const float*)d_in[10];
    const float* b1 = (const float*)d_in[11];
    const float* W2 = (const float*)d_in[12];
    const float* b2 = (const float*)d_in[13];
    const float* V1 = (const float*)d_in[14];
    const float* c1 = (const float*)d_in[15];
    const float* V2 = (const float*)d_in[16];
    const float* c2 = (const float*)d_in[17];

    float* ws = (float*)d_ws;
    int* ectrl = (int*)d_ws;              // 8 counters (zeroed each launch)
    float* x    = ws + 256;
    float* gxf  = x + T_LEN * 512;
    float* gxb  = gxf + T_LEN * 2048;
    float* fwd  = gxb + T_LEN * 2048;
    float* bwd  = fwd + T_LEN * 512;      // fwd,bwd,fwdm,bwdm contiguous (poisoned together)
    float* fwdm = bwd + T_LEN * 512;
    float* bwdm = fwdm + T_LEN * 512;
    float* A    = bwdm + T_LEN * 512;
    float* B    = A + T_LEN * 1024;
    float* AV   = B + T_LEN * 1024;
    float* BV   = AV + T_LEN * 1024;

    hipMemsetAsync(d_ws, 0, 256, stream);
    k_poison<<<(4 * T_LEN * 512) / 256, 256, 0, stream>>>(fwd);
    k_embed<<<T_LEN, 128, 0, stream>>>(tag_ids, word_ids, tag_emb, word_emb, x);
    k_gx<<<dim3(32, 13, 2), 256, 0, stream>>>(x, Wf_ih, bf, Wb_ih, bb, gxf, gxb);

    {
        void* args[] = {(void*)&gxf, (void*)&gxb, (void*)&Wf_hh, (void*)&Wb_hh,
                        (void*)&fwd, (void*)&bwd, (void*)&fwdm, (void*)&bwdm,
                        (void*)&ectrl};
        hipError_t e = hipLaunchCooperativeKernel((const void*)k_scan_xcd, dim3(256),
                                                  dim3(256), args, 0, stream);
        if (e != hipSuccess) {
            // proven LLC-only path (R6, ~870us)
            k_scan<<<64, 256, 0, stream>>>(gxf, gxb, Wf_hh, Wb_hh, fwd, bwd);
        }
    }

    k_tables<<<dim3(16, 13, 4), 256, 0, stream>>>(fwd, bwd, W1, V1, A, B, AV, BV);
    k_span<<<NSPAN / 64, 256, 0, stream>>>(A, B, AV, BV, W2, b1, b2, V2, c1, c2,
                                           (float*)d_out);
}

// Round 10
// 2396.387 us; speedup vs baseline: 1.1589x; 1.1589x over previous
//
#include <hip/hip_runtime.h>

#define T_LEN 386
#define NW 192          // worker blocks (bid 64..255)

typedef float v4f __attribute__((ext_vector_type(4)));

// ---- LLC ops (sc0 sc1: device scope, cross-XCD coherent) ----
__device__ inline void llc_load8(const float* p, v4f& a, v4f& b) {
    asm volatile("global_load_dwordx4 %0, %2, off sc0 sc1\n\t"
                 "global_load_dwordx4 %1, %2, off offset:16 sc0 sc1\n\t"
                 "s_waitcnt vmcnt(0)"
                 : "=&v"(a), "=&v"(b) : "v"(p) : "memory");
}
__device__ inline void llc_store4(float* p, v4f v) {
    asm volatile("global_store_dwordx4 %0, %1, off sc0 sc1"
                 :: "v"(p), "v"(v) : "memory");
}
__device__ inline int llc_load_int(const int* p) {
    int v;
    asm volatile("global_load_dword %0, %1, off sc0 sc1\n\t"
                 "s_waitcnt vmcnt(0)" : "=v"(v) : "v"(p) : "memory");
    return v;
}
__device__ inline void slow_sleep() {
    __builtin_amdgcn_s_sleep(127);
    __builtin_amdgcn_s_sleep(127);   // ~7us between poll rounds
}

__device__ inline float fsigmoid(float x) { return 1.f / (1.f + __expf(-x)); }
__device__ inline float ftanh(float x) {
    x = fminf(fmaxf(x, -15.f), 15.f);
    float e = __expf(2.f * x);
    return (e - 1.f) / (e + 1.f);
}
__device__ inline int gfun(int t) { int v = 2 * t - 385; return v < 0 ? -v : v; }
// ring in which the TABLE row t is released = ring of its 32-row t-tile
__device__ inline int tring(int t) {
    int tb = (t >> 5) << 5;
    int te = min(tb + 31, 385);
    return max(gfun(tb), gfun(te)) >> 6;
}

// ---------------- kernel 1: embedding concat ----------------
__global__ void k_embed(const int* __restrict__ tag_ids, const int* __restrict__ word_ids,
                        const float* __restrict__ tag_emb, const float* __restrict__ word_emb,
                        float* __restrict__ x) {
    int t = blockIdx.x;
    int tid = threadIdx.x; // 128
    int tr = tag_ids[t], wr = word_ids[t];
    x[t * 512 + tid] = tag_emb[tr * 128 + tid];
    for (int j = tid; j < 384; j += 128)
        x[t * 512 + 128 + j] = word_emb[wr * 384 + j];
}

// ---------------- kernel 2: gx = x(rev) @ Wih^T + b ----------------
__global__ void k_gx(const float* __restrict__ x,
                     const float* __restrict__ Wf, const float* __restrict__ bf,
                     const float* __restrict__ Wb, const float* __restrict__ bb,
                     float* __restrict__ gxf, float* __restrict__ gxb) {
    __shared__ float xs[32 * 512];
    int dir = blockIdx.z;
    const float* W = dir ? Wb : Wf;
    const float* bias = dir ? bb : bf;
    float* out = dir ? gxb : gxf;
    int nbase = blockIdx.x * 64;
    int tbase = blockIdx.y * 32;
    int tid = threadIdx.x;

    for (int i = tid; i < 32 * 128; i += 256) {
        int row = i >> 7, c4 = i & 127;
        int t = tbase + row;
        float4 v = make_float4(0.f, 0.f, 0.f, 0.f);
        if (t < T_LEN) {
            int src = dir ? (T_LEN - 1 - t) : t;
            v = ((const float4*)(x + src * 512))[c4];
        }
        ((float4*)xs)[i] = v;
    }
    __syncthreads();

    int col = tid >> 2;
    int kq = tid & 3;
    int n = nbase + col;
    const float4* wrow = (const float4*)(W + (long)n * 512);
    float acc[32];
#pragma unroll
    for (int r = 0; r < 32; ++r) acc[r] = 0.f;
#pragma unroll 2
    for (int it = 0; it < 32; ++it) {
        int k4 = it * 4 + kq;
        float4 w = wrow[k4];
#pragma unroll
        for (int r = 0; r < 32; ++r) {
            float4 xv = ((const float4*)(xs + r * 512))[k4];
            acc[r] += w.x * xv.x + w.y * xv.y + w.z * xv.z + w.w * xv.w;
        }
    }
#pragma unroll
    for (int r = 0; r < 32; ++r) {
        float v = acc[r];
        v += __shfl_xor(v, 1, 4);
        v += __shfl_xor(v, 2, 4);
        acc[r] = v;
    }
    if (kq == 0) {
        float bv = bias[n];
        for (int r = 0; r < 32; ++r) {
            int t = tbase + r;
            if (t < T_LEN) out[t * 2048 + n] = acc[r] + bv;
        }
    }
}

// ---------------- kernel 2b: poison fwd/bwd with sentinel 2.0f ----------------
__global__ void k_poison(float* __restrict__ st) {
    int i = blockIdx.x * 256 + threadIdx.x;
    __hip_atomic_store(st + i, 2.0f, __ATOMIC_RELAXED, __HIP_MEMORY_SCOPE_AGENT);
}

// ================= worker sub-kernels (device functions) =================

__device__ void tables_tile(char* smem, int ti, int z, int nx,
                            const float* fwd, const float* bwd,
                            const float* W1, const float* V1,
                            float* A, float* B, float* AV, float* BV,
                            int* rdy) {
    float* xs = (float*)smem;                    // 64KB
    int tid = threadIdx.x;
    int tbase = ti * 32;
    int tend = min(tbase + 31, 385);
    const float* S = (z & 1) ? bwd : fwd;
    const int* rdys = rdy + (z & 1) * 386;       // rdy_f / rdy_b
    int* rdyT = rdy + 772;
    const float* W = ((z >> 1) ? V1 : W1) + (z & 1) * 512 * 1024;
    float* outp = z == 0 ? A : z == 1 ? B : z == 2 ? AV : BV;

    // Monotone release: scan blocks bump rows in step order, so one row
    // (last-released of this tile) gates the whole tile. One lane polls.
    if (tid == 0) {
        int gaterow = (z & 1) ? tbase : tend;    // bwd releases high->low
        int gg = 0;
        while (llc_load_int(rdys + gaterow) < 128 && ++gg < (1 << 18))
            slow_sleep();
    }
    __syncthreads();

    // stage rows via LLC loads (bypass possibly-sentinel-stale L1/L2)
    for (int i = tid; i < 32 * 64; i += 256) {
        int row = i >> 6, c8 = i & 63;
        int t = tbase + row;
        v4f a = {0.f, 0.f, 0.f, 0.f}, b = {0.f, 0.f, 0.f, 0.f};
        if (t < T_LEN) llc_load8(S + (long)t * 512 + c8 * 8, a, b);
        *(v4f*)(xs + row * 512 + c8 * 8) = a;
        *(v4f*)(xs + row * 512 + c8 * 8 + 4) = b;
    }
    __syncthreads();

    int cg = tid & 15, rg = tid >> 4;
    int n = nx * 64 + cg * 4;
    float4 acc0 = make_float4(0.f, 0.f, 0.f, 0.f);
    float4 acc1 = make_float4(0.f, 0.f, 0.f, 0.f);
#pragma unroll 4
    for (int k = 0; k < 512; ++k) {
        float4 wv = *(const float4*)(W + (long)k * 1024 + n);
        float x0 = xs[(rg * 2) * 512 + k];
        float x1 = xs[(rg * 2 + 1) * 512 + k];
        acc0.x += x0 * wv.x; acc0.y += x0 * wv.y; acc0.z += x0 * wv.z; acc0.w += x0 * wv.w;
        acc1.x += x1 * wv.x; acc1.y += x1 * wv.y; acc1.z += x1 * wv.z; acc1.w += x1 * wv.w;
    }
    int t0 = tbase + rg * 2, t1 = t0 + 1;
    if (t0 < T_LEN) { v4f v = {acc0.x, acc0.y, acc0.z, acc0.w}; llc_store4(outp + (long)t0 * 1024 + n, v); }
    if (t1 < T_LEN) { v4f v = {acc1.x, acc1.y, acc1.z, acc1.w}; llc_store4(outp + (long)t1 * 1024 + n, v); }
    asm volatile("s_waitcnt vmcnt(0)" ::: "memory");
    __syncthreads();
    if (tid < 32) {
        int t = tbase + tid;
        if (t < T_LEN)
            __hip_atomic_fetch_add(rdyT + z * 386 + t, 1, __ATOMIC_RELAXED,
                                   __HIP_MEMORY_SCOPE_AGENT);
    }
}

__device__ void span_tile(char* smem, int l, int rbase, int rend,
                          const float* A, const float* B,
                          const float* AV, const float* BV,
                          const float* W2, const float* b1, const float* b2,
                          const float* V2, const float* c1, const float* c2,
                          const int* rdy, float* out) {
    float (*hid)[36] = (float(*)[36])smem;       // 9216B
    float* w2s = (float*)smem + 64 * 36;         // 16KB
    const int* rdyT = rdy + 772;
    int tid = threadIdx.x;
    int cnt = rend - rbase + 1;

    // wait for needed table rows (==16 n-chunks each), sleepy polls
    {
        int t1 = -1, t2 = -1;
        if (tid < 64) { int t = rbase + tid; if (t <= rend) { t1 = t; t2 = 2 * 386 + t; } }
        else if (tid < 128) { int t = rbase + 1 + (tid - 64); if (t <= rend + 1) { t1 = 386 + t; t2 = 3 * 386 + t; } }
        else if (tid == 128) { t1 = l; t2 = 2 * 386 + l; }
        else if (tid == 129) { t1 = 386 + l + 1; t2 = 3 * 386 + l + 1; }
        if (t1 >= 0) {
            int gg = 0;
            while ((llc_load_int(rdyT + t1) < 16 || llc_load_int(rdyT + t2) < 16)
                   && ++gg < (1 << 18))
                slow_sleep();
        }
    }
    __syncthreads();

    float acc[8][4];
#pragma unroll
    for (int a = 0; a < 8; ++a)
#pragma unroll
        for (int b = 0; b < 4; ++b) acc[a][b] = 0.f;
    float vacc[2] = {0.f, 0.f};
    int chg = tid & 31, sgm = tid >> 5;
    int kq = tid & 7, sgb = tid >> 3;
    int sp0 = sgb * 2, sp1 = sgb * 2 + 1;
    int r0 = rbase + min(sp0, cnt - 1);
    int r1 = rbase + min(sp1, cnt - 1);
    long soff = (long)l * 384 - (long)l * (l - 1) / 2 + (rbase - l - 1);

    for (int kb = 0; kb < 1024; kb += 32) {
        if (kb) __syncthreads();
        for (int i = tid; i < 32 * 128 / 4; i += 256)
            ((float4*)w2s)[i] = ((const float4*)(W2 + kb * 128))[i];
        int ko = kb + kq * 4;
        float4 bv = *(const float4*)(b1 + ko);
        float4 cv = *(const float4*)(c1 + ko);
        float4 v2 = *(const float4*)(V2 + ko);
        float4 al = *(const float4*)(A + (long)l * 1024 + ko);
        float4 bl = *(const float4*)(B + (long)(l + 1) * 1024 + ko);
        float4 vl = *(const float4*)(AV + (long)l * 1024 + ko);
        float4 ul = *(const float4*)(BV + (long)(l + 1) * 1024 + ko);
#pragma unroll
        for (int si = 0; si < 2; ++si) {
            int r = si ? r1 : r0;
            int sp = si ? sp1 : sp0;
            float4 ar = *(const float4*)(A + (long)r * 1024 + ko);
            float4 br = *(const float4*)(B + (long)(r + 1) * 1024 + ko);
            float4 hx;
            hx.x = fmaxf(ar.x - al.x + bl.x - br.x + bv.x, 0.f);
            hx.y = fmaxf(ar.y - al.y + bl.y - br.y + bv.y, 0.f);
            hx.z = fmaxf(ar.z - al.z + bl.z - br.z + bv.z, 0.f);
            hx.w = fmaxf(ar.w - al.w + bl.w - br.w + bv.w, 0.f);
            *(float4*)&hid[sp][kq * 4] = hx;
            float4 vr = *(const float4*)(AV + (long)r * 1024 + ko);
            float4 ur = *(const float4*)(BV + (long)(r + 1) * 1024 + ko);
            float h0 = fmaxf(vr.x - vl.x + ul.x - ur.x + cv.x, 0.f);
            float h1 = fmaxf(vr.y - vl.y + ul.y - ur.y + cv.y, 0.f);
            float h2 = fmaxf(vr.z - vl.z + ul.z - ur.z + cv.z, 0.f);
            float h3 = fmaxf(vr.w - vl.w + ul.w - ur.w + cv.w, 0.f);
            vacc[si] += h0 * v2.x + h1 * v2.y + h2 * v2.z + h3 * v2.w;
        }
        __syncthreads();
#pragma unroll 2
        for (int k = 0; k < 32; k += 4) {
            float4 h4[8];
#pragma unroll
            for (int j2 = 0; j2 < 8; ++j2)
                h4[j2] = *(const float4*)&hid[sgm * 8 + j2][k];
#pragma unroll
            for (int kk = 0; kk < 4; ++kk) {
                float4 wv = *(const float4*)&w2s[(k + kk) * 128 + chg * 4];
#pragma unroll
                for (int j2 = 0; j2 < 8; ++j2) {
                    float hx = (&h4[j2].x)[kk];
                    acc[j2][0] += hx * wv.x; acc[j2][1] += hx * wv.y;
                    acc[j2][2] += hx * wv.z; acc[j2][3] += hx * wv.w;
                }
            }
        }
    }

    float4 b2v = *(const float4*)(b2 + chg * 4);
#pragma unroll
    for (int j2 = 0; j2 < 8; ++j2) {
        int spn = sgm * 8 + j2;
        if (spn < cnt) {
            float* o = out + (soff + spn) * 129 + chg * 4;
            o[0] = acc[j2][0] + b2v.x; o[1] = acc[j2][1] + b2v.y;
            o[2] = acc[j2][2] + b2v.z; o[3] = acc[j2][3] + b2v.w;
        }
    }
    float c2v = c2[0];
#pragma unroll
    for (int si = 0; si < 2; ++si) {
        int spn = sgb * 2 + si;
        float v = vacc[si];
        v += __shfl_xor(v, 4, 8);
        v += __shfl_xor(v, 2, 8);
        v += __shfl_xor(v, 1, 8);
        if (kq == 0 && spn < cnt) out[(soff + spn) * 129 + 128] = v + c2v;
    }
    __syncthreads();   // protect smem reuse by next tile
}

// ================= mega-kernel: scan ∥ tables ∥ span =================
__launch_bounds__(256, 1)
__global__ void k_mega(const float* __restrict__ gxf, const float* __restrict__ gxb,
                       const float* __restrict__ Wfhh, const float* __restrict__ Wbhh,
                       const float* __restrict__ W1, const float* __restrict__ V1,
                       const float* __restrict__ W2, const float* __restrict__ b1,
                       const float* __restrict__ b2, const float* __restrict__ V2,
                       const float* __restrict__ c1, const float* __restrict__ c2,
                       float* fwd, float* bwd,
                       float* A, float* B, float* AV, float* BV,
                       int* rdy, float* out) {
    __shared__ __align__(16) char smem_raw[102912];
    int bid = blockIdx.x;
    int tid = threadIdx.x;

    if (bid < 64) {
        // ---------------- scan role (R6-proven LLC data-as-flag) ----------------
        float* gx_sh = (float*)smem_raw;            // [T_LEN][64]
        float* h_base = gx_sh + T_LEN * 64;         // [2][512]
        int dir = bid >> 5;
        int w = bid & 31;
        const float* gx = dir ? gxb : gxf;
        const float* Whh = dir ? Wbhh : Wfhh;
        float* st = dir ? bwd : fwd;
        int* rdyd = rdy + dir * 386;

        for (int idx = tid; idx < T_LEN * 64; idx += 256) {
            int t = idx >> 6, j = idx & 63;
            gx_sh[idx] = gx[t * 2048 + (j >> 4) * 512 + w * 16 + (j & 15)];
        }

        int u = tid >> 4;
        int r = tid & 15;
        int g = r >> 2;
        int kq = r & 3;
        int wave = tid >> 6;
        int grow = g * 512 + w * 16 + u;
        float4 wreg[32];
        const float4* wsrc = (const float4*)(Whh + (long)grow * 512);
#pragma unroll
        for (int it = 0; it < 32; ++it) wreg[it] = wsrc[it * 4 + kq];
        float c = 0.f;
        __syncthreads();

        for (int ts = 0; ts < T_LEN; ++ts) {
            float* hbuf = h_base + (ts & 1) * 512;
            if (tid < 64) {
                if (ts == 0) {
                    float4 z = make_float4(0.f, 0.f, 0.f, 0.f);
                    *(float4*)(hbuf + tid * 8) = z;
                    *(float4*)(hbuf + tid * 8 + 4) = z;
                } else {
                    int srow = dir ? (T_LEN - ts) : (ts - 1);
                    const float* src = st + srow * 512 + tid * 8;
                    v4f a, b;
                    int gg = 0;
                    for (;;) {
                        llc_load8(src, a, b);
                        bool bad = a.x == 2.f || a.y == 2.f || a.z == 2.f || a.w == 2.f ||
                                   b.x == 2.f || b.y == 2.f || b.z == 2.f || b.w == 2.f;
                        if (!bad || ++gg > (1 << 23)) break;
                    }
                    *(v4f*)(hbuf + tid * 8) = a;
                    *(v4f*)(hbuf + tid * 8 + 4) = b;
                }
            }
            __syncthreads();

            const float4* hv = (const float4*)hbuf;
            float a0 = 0.f, a1 = 0.f, a2 = 0.f, a3 = 0.f;
#pragma unroll
            for (int it = 0; it < 32; ++it) {
                float4 h4 = hv[it * 4 + kq];
                float4 w4 = wreg[it];
                a0 += w4.x * h4.x; a1 += w4.y * h4.y;
                a2 += w4.z * h4.z; a3 += w4.w * h4.w;
            }
            float v = (a0 + a1) + (a2 + a3);
            v += __shfl_xor(v, 1, 4);
            v += __shfl_xor(v, 2, 4);
            float gi = __shfl(v, (u & 3) * 16 + 0, 64)  + gx_sh[ts * 64 + u];
            float gf = __shfl(v, (u & 3) * 16 + 4, 64)  + gx_sh[ts * 64 + 16 + u];
            float gg_ = __shfl(v, (u & 3) * 16 + 8, 64) + gx_sh[ts * 64 + 32 + u];
            float go = __shfl(v, (u & 3) * 16 + 12, 64) + gx_sh[ts * 64 + 48 + u];
            float i_ = fsigmoid(gi);
            float f_ = fsigmoid(gf);
            float o_ = fsigmoid(go);
            c = f_ * c + i_ * ftanh(gg_);
            float h = o_ * ftanh(c);
            // wave-gather 4 unit-h values -> one dwordx4 store + rdy bump
            float h0 = __shfl(h, 0, 64);
            float h1 = __shfl(h, 16, 64);
            float h2 = __shfl(h, 32, 64);
            float h3 = __shfl(h, 48, 64);
            if ((tid & 63) == 0) {
                int drow = dir ? (T_LEN - 1 - ts) : ts;
                v4f hv4 = {h0, h1, h2, h3};
                llc_store4(st + drow * 512 + w * 16 + wave * 4, hv4);
                asm volatile("s_waitcnt vmcnt(0)" ::: "memory");
                __hip_atomic_fetch_add(rdyd + drow, 1, __ATOMIC_RELAXED,
                                       __HIP_MEMORY_SCOPE_AGENT);
            }
        }
        return;
    }

    // ---------------- worker role: tables + span in table-release ring order ----------------
    int wk = bid - 64;
    for (int p = 0; p < 7; ++p) {
        // tables tiles of ring p   (13 t-tiles x 4 arrays x 16 n-chunks = 832)
        for (int idx = wk; idx < 832; idx += NW) {
            int ti = idx >> 6;
            int z = (idx >> 4) & 3;
            int nx = idx & 15;
            int tbase = ti * 32;
            int tend = min(tbase + 31, 385);
            int Kt = max(gfun(tbase), gfun(tend)) >> 6;   // == tring of this tile
            if (Kt != p) continue;
            tables_tile(smem_raw, ti, z, nx, fwd, bwd, W1, V1, A, B, AV, BV, rdy);
        }
        // span tiles of ring p, ring = max TABLE-release ring of all needed rows
        for (int idx = wk; idx < 384 * 6; idx += NW) {
            int l = idx / 6, j = idx % 6;
            int rbase = l + 1 + 64 * j;
            if (rbase > 384) continue;
            int rend = min(rbase + 63, 384);
            int K = max(tring(l), tring(l + 1));
            for (int tt = (rbase >> 5); tt <= ((rend + 1) >> 5); ++tt) {
                int tb = tt * 32, te = min(tb + 31, 385);
                K = max(K, max(gfun(tb), gfun(te)) >> 6);
            }
            if (K != p) continue;
            span_tile(smem_raw, l, rbase, rend, A, B, AV, BV,
                      W2, b1, b2, V2, c1, c2, rdy, out);
        }
    }
}

extern "C" void kernel_launch(void* const* d_in, const int* in_sizes, int n_in,
                              void* d_out, int out_size, void* d_ws, size_t ws_size,
                              hipStream_t stream) {
    const int* tag_ids  = (const int*)d_in[0];
    const int* word_ids = (const int*)d_in[1];
    const float* tag_emb  = (const float*)d_in[2];
    const float* word_emb = (const float*)d_in[3];
    const float* Wf_ih = (const float*)d_in[4];
    const float* Wf_hh = (const float*)d_in[5];
    const float* bf    = (const float*)d_in[6];
    const float* Wb_ih = (const float*)d_in[7];
    const float* Wb_hh = (const float*)d_in[8];
    const float* bb    = (const float*)d_in[9];
    const float* W1 = (const float*)d_in[10];
    const float* b1 = (const float*)d_in[11];
    const float* W2 = (const float*)d_in[12];
    const float* b2 = (const float*)d_in[13];
    const float* V1 = (const float*)d_in[14];
    const float* c1 = (const float*)d_in[15];
    const float* V2 = (const float*)d_in[16];
    const float* c2 = (const float*)d_in[17];

    int* rdy = (int*)d_ws;                       // 772 + 4*386 = 2316 ints
    float* base = (float*)d_ws + 4096;           // 16KB offset
    float* x   = base;
    float* gxf = x + T_LEN * 512;
    float* gxb = gxf + T_LEN * 2048;
    float* fwd = gxb + T_LEN * 2048;
    float* bwd = fwd + T_LEN * 512;              // fwd,bwd contiguous (poisoned together)
    float* A   = bwd + T_LEN * 512;
    float* B   = A + T_LEN * 1024;
    float* AV  = B + T_LEN * 1024;
    float* BV  = AV + T_LEN * 1024;

    hipMemsetAsync(d_ws, 0, 2316 * 4, stream);                       // rdy counters
    k_poison<<<(2 * T_LEN * 512) / 256, 256, 0, stream>>>(fwd);      // h sentinels
    k_embed<<<T_LEN, 128, 0, stream>>>(tag_ids, word_ids, tag_emb, word_emb, x);
    k_gx<<<dim3(32, 13, 2), 256, 0, stream>>>(x, Wf_ih, bf, Wb_ih, bb, gxf, gxb);
    k_mega<<<256, 256, 0, stream>>>(gxf, gxb, Wf_hh, Wb_hh, W1, V1, W2, b1, b2,
                                    V2, c1, c2, fwd, bwd, A, B, AV, BV, rdy,
                                    (float*)d_out);
}

// Round 11
// 1409.678 us; speedup vs baseline: 1.9701x; 1.7000x over previous
//
#include <hip/hip_runtime.h>

#define T_LEN 386
#define NSPAN 73920

typedef float v4f __attribute__((ext_vector_type(4)));

// ---- LLC ops (sc0 sc1: device scope) ----
__device__ inline void llc_load8(const float* p, v4f& a, v4f& b) {
    asm volatile("global_load_dwordx4 %0, %2, off sc0 sc1\n\t"
                 "global_load_dwordx4 %1, %2, off offset:16 sc0 sc1\n\t"
                 "s_waitcnt vmcnt(0)"
                 : "=&v"(a), "=&v"(b) : "v"(p) : "memory");
}
__device__ inline void llc_store1(float* p, float v) {
    asm volatile("global_store_dword %0, %1, off sc0 sc1"
                 :: "v"(p), "v"(v) : "memory");
}

__device__ inline float fsigmoid(float x) { return 1.f / (1.f + __expf(-x)); }
__device__ inline float ftanh(float x) {
    x = fminf(fmaxf(x, -15.f), 15.f);
    float e = __expf(2.f * x);
    return (e - 1.f) / (e + 1.f);
}

// ---------------- kernel 1: embedding concat ----------------
__global__ void k_embed(const int* __restrict__ tag_ids, const int* __restrict__ word_ids,
                        const float* __restrict__ tag_emb, const float* __restrict__ word_emb,
                        float* __restrict__ x) {
    int t = blockIdx.x;
    int tid = threadIdx.x; // 128
    int tr = tag_ids[t], wr = word_ids[t];
    x[t * 512 + tid] = tag_emb[tr * 128 + tid];
    for (int j = tid; j < 384; j += 128)
        x[t * 512 + 128 + j] = word_emb[wr * 384 + j];
}

// ---------------- kernel 2: gx = x(rev) @ Wih^T + b ----------------
// grid (32 n-tiles, 13 t-tiles, 2 dirs), block 256
__global__ void k_gx(const float* __restrict__ x,
                     const float* __restrict__ Wf, const float* __restrict__ bf,
                     const float* __restrict__ Wb, const float* __restrict__ bb,
                     float* __restrict__ gxf, float* __restrict__ gxb) {
    __shared__ float xs[32 * 512];
    int dir = blockIdx.z;
    const float* W = dir ? Wb : Wf;
    const float* bias = dir ? bb : bf;
    float* out = dir ? gxb : gxf;
    int nbase = blockIdx.x * 64;
    int tbase = blockIdx.y * 32;
    int tid = threadIdx.x;

    for (int i = tid; i < 32 * 128; i += 256) {
        int row = i >> 7, c4 = i & 127;
        int t = tbase + row;
        float4 v = make_float4(0.f, 0.f, 0.f, 0.f);
        if (t < T_LEN) {
            int src = dir ? (T_LEN - 1 - t) : t;
            v = ((const float4*)(x + src * 512))[c4];
        }
        ((float4*)xs)[i] = v;
    }
    __syncthreads();

    int col = tid >> 2;
    int kq = tid & 3;
    int n = nbase + col;
    const float4* wrow = (const float4*)(W + (long)n * 512);
    float acc[32];
#pragma unroll
    for (int r = 0; r < 32; ++r) acc[r] = 0.f;
#pragma unroll 2
    for (int it = 0; it < 32; ++it) {
        int k4 = it * 4 + kq;
        float4 w = wrow[k4];
#pragma unroll
        for (int r = 0; r < 32; ++r) {
            float4 xv = ((const float4*)(xs + r * 512))[k4];
            acc[r] += w.x * xv.x + w.y * xv.y + w.z * xv.z + w.w * xv.w;
        }
    }
#pragma unroll
    for (int r = 0; r < 32; ++r) {
        float v = acc[r];
        v += __shfl_xor(v, 1, 4);
        v += __shfl_xor(v, 2, 4);
        acc[r] = v;
    }
    if (kq == 0) {
        float bv = bias[n];
        for (int r = 0; r < 32; ++r) {
            int t = tbase + r;
            if (t < T_LEN) out[t * 2048 + n] = acc[r] + bv;
        }
    }
}

// ---------------- kernel 2b: poison fwd/bwd with sentinel 2.0f ----------------
__global__ void k_poison(float* __restrict__ st) {
    int i = blockIdx.x * 256 + threadIdx.x;
    __hip_atomic_store(st + i, 2.0f, __ATOMIC_RELAXED, __HIP_MEMORY_SCOPE_AGENT);
}

// ---------------- kernel 3: persistent bidirectional LSTM scan ----------------
// grid 64 (2 dirs * 32 WGs), block 320 = 4 compute waves + 1 FETCHER wave.
// Compute waves: unchanged R6 math (16 lanes/unit, Whh slice in regs, gx in
// LDS, c in regs). Fetcher wave polls the NEXT step's h row (the one all 32
// WGs are producing during this step) into the other half of a double-
// buffered h_sh, overlapping poll latency with compute. One barrier/step.
// Cross-block protocol identical to R6: data-as-flag via LLC (sentinel 2.0f).
__launch_bounds__(320, 1)
__global__ void k_scan(const float* __restrict__ gxf, const float* __restrict__ gxb,
                       const float* __restrict__ Wfhh, const float* __restrict__ Wbhh,
                       float* fwd, float* bwd) {
    __shared__ float gx_sh[T_LEN * 64];
    __shared__ float h_sh[2][512];
    int bid = blockIdx.x;
    int dir = bid >> 5;
    int w = bid & 31;
    int tid = threadIdx.x;
    const float* gx = dir ? gxb : gxf;
    const float* Whh = dir ? Wbhh : Wfhh;
    float* st = dir ? bwd : fwd;

    for (int idx = tid; idx < T_LEN * 64; idx += 320) {
        int t = idx >> 6, j = idx & 63;
        gx_sh[idx] = gx[t * 2048 + (j >> 4) * 512 + w * 16 + (j & 15)];
    }

    int u = tid >> 4;  // hidden unit 0..15 (compute threads)
    int r = tid & 15;  // lane-in-unit
    int kq = r & 3;    // k-slice
    float4 wreg[32];
    float c = 0.f;
    if (tid < 256) {
        int g = r >> 2;
        int grow = g * 512 + w * 16 + u;
        const float4* wsrc = (const float4*)(Whh + (long)grow * 512);
#pragma unroll
        for (int it = 0; it < 32; ++it) wreg[it] = wsrc[it * 4 + kq];
    } else {
        // fetcher: zero-init h_sh[0] (input of step 0)
        int fl = tid - 256;
        float4 z = make_float4(0.f, 0.f, 0.f, 0.f);
        *(float4*)(&h_sh[0][fl * 8]) = z;
        *(float4*)(&h_sh[0][fl * 8 + 4]) = z;
    }
    __syncthreads();

    int cur = 0;
    for (int ts = 0; ts < T_LEN; ++ts) {
        int drow = dir ? (T_LEN - 1 - ts) : ts;   // row produced this step
        if (tid < 256) {
            const float4* hv = (const float4*)h_sh[cur];
            float a0 = 0.f, a1 = 0.f, a2 = 0.f, a3 = 0.f;
#pragma unroll
            for (int it = 0; it < 32; ++it) {
                float4 h4 = hv[it * 4 + kq];
                float4 w4 = wreg[it];
                a0 += w4.x * h4.x; a1 += w4.y * h4.y;
                a2 += w4.z * h4.z; a3 += w4.w * h4.w;
            }
            float v = (a0 + a1) + (a2 + a3);
            v += __shfl_xor(v, 1, 4);
            v += __shfl_xor(v, 2, 4);
            // gather the 4 gate sums within the 16-lane unit group
            float gi = __shfl(v, (u & 3) * 16 + 0, 64)  + gx_sh[ts * 64 + u];
            float gf = __shfl(v, (u & 3) * 16 + 4, 64)  + gx_sh[ts * 64 + 16 + u];
            float gg = __shfl(v, (u & 3) * 16 + 8, 64)  + gx_sh[ts * 64 + 32 + u];
            float go = __shfl(v, (u & 3) * 16 + 12, 64) + gx_sh[ts * 64 + 48 + u];
            float i_ = fsigmoid(gi);
            float f_ = fsigmoid(gf);
            float o_ = fsigmoid(go);
            c = f_ * c + i_ * ftanh(gg);
            float h = o_ * ftanh(c);
            if (r == 0)
                llc_store1(st + drow * 512 + w * 16 + u, h);
        } else if (ts < T_LEN - 1) {
            // fetcher: poll h(ts) = input of step ts+1 into h_sh[cur^1].
            // Polls run concurrently with this block's compute of step ts.
            int fl = tid - 256;
            const float* src = st + drow * 512 + fl * 8;
            v4f a, b;
            int gg = 0;
            for (;;) {
                llc_load8(src, a, b);
                bool bad = a.x == 2.f || a.y == 2.f || a.z == 2.f || a.w == 2.f ||
                           b.x == 2.f || b.y == 2.f || b.z == 2.f || b.w == 2.f;
                if (!bad || ++gg > (1 << 23)) break;
            }
            *(v4f*)(&h_sh[cur ^ 1][fl * 8]) = a;
            *(v4f*)(&h_sh[cur ^ 1][fl * 8 + 4]) = b;
        }
        __syncthreads();
        cur ^= 1;
    }
}

// ---------------- kernel 4: position tables  C[386,1024] = S[386,512] @ Wpart ----------------
// grid (16 n-tiles, 13 t-tiles, 4 tables), block 256
__global__ void k_tables(const float* __restrict__ fwd, const float* __restrict__ bwd,
                         const float* __restrict__ W1, const float* __restrict__ V1,
                         float* __restrict__ A, float* __restrict__ B,
                         float* __restrict__ AV, float* __restrict__ BV) {
    __shared__ float xs[32 * 512];
    int which = blockIdx.z;
    const float* S = (which & 1) ? bwd : fwd;
    const float* W = ((which >> 1) ? V1 : W1) + (which & 1) * 512 * 1024;
    float* out = which == 0 ? A : which == 1 ? B : which == 2 ? AV : BV;
    int nbase = blockIdx.x * 64, tbase = blockIdx.y * 32;
    int tid = threadIdx.x;

    for (int i = tid; i < 32 * 128; i += 256) {
        int row = i >> 7, c4 = i & 127;
        int t = tbase + row;
        float4 v = make_float4(0.f, 0.f, 0.f, 0.f);
        if (t < T_LEN) v = ((const float4*)(S + t * 512))[c4];
        ((float4*)xs)[i] = v;
    }
    __syncthreads();

    int cg = tid & 15;
    int rg = tid >> 4;
    int n = nbase + cg * 4;
    float4 acc0 = make_float4(0.f, 0.f, 0.f, 0.f);
    float4 acc1 = make_float4(0.f, 0.f, 0.f, 0.f);
#pragma unroll 4
    for (int k = 0; k < 512; ++k) {
        float4 wv = *(const float4*)(W + (long)k * 1024 + n);
        float x0 = xs[(rg * 2) * 512 + k];
        float x1 = xs[(rg * 2 + 1) * 512 + k];
        acc0.x += x0 * wv.x; acc0.y += x0 * wv.y; acc0.z += x0 * wv.z; acc0.w += x0 * wv.w;
        acc1.x += x1 * wv.x; acc1.y += x1 * wv.y; acc1.z += x1 * wv.z; acc1.w += x1 * wv.w;
    }
    int t0 = tbase + rg * 2, t1 = t0 + 1;
    if (t0 < T_LEN) *(float4*)(out + (long)t0 * 1024 + n) = acc0;
    if (t1 < T_LEN) *(float4*)(out + (long)t1 * 1024 + n) = acc1;
}

// ---------------- kernel 5: fused span FFN ----------------
// grid NSPAN/64 blocks, 256 threads, 4 blocks/CU (26KB LDS). Per WG: 64 spans.
#define TS 64
#define KC 32
__launch_bounds__(256, 4)
__global__ void k_span(const float* __restrict__ A, const float* __restrict__ B,
                       const float* __restrict__ AV, const float* __restrict__ BV,
                       const float* __restrict__ W2, const float* __restrict__ b1,
                       const float* __restrict__ b2, const float* __restrict__ V2,
                       const float* __restrict__ c1, const float* __restrict__ c2,
                       float* __restrict__ out) {
    __shared__ float hid[TS][KC + 4];
    __shared__ float w2s[KC * 128];
    __shared__ int ls[TS], rs[TS];
    int tid = threadIdx.x;
    int wg = blockIdx.x;

    if (tid < TS) {
        int s = wg * TS + tid;
        float disc = 769.0f * 769.0f - 8.0f * (float)s;
        int l = (int)floorf((769.0f - sqrtf(disc)) * 0.5f);
        if (l < 0) l = 0;
        if (l > 383) l = 383;
#define OFF(L) ((L) * 384 - ((L) * ((L) - 1)) / 2)
        while (l + 1 <= 384 && OFF(l + 1) <= s) ++l;
        while (l > 0 && OFF(l) > s) --l;
        int r = l + 1 + (s - OFF(l));
        ls[tid] = l; rs[tid] = r;
    }
    float acc[8][4];
#pragma unroll
    for (int a = 0; a < 8; ++a)
#pragma unroll
        for (int b = 0; b < 4; ++b) acc[a][b] = 0.f;
    float vacc[2] = {0.f, 0.f};
    int chg = tid & 31, sgm = tid >> 5;
    int kq = tid & 7, sgb = tid >> 3;
    __syncthreads();

    for (int kb = 0; kb < 1024; kb += KC) {
        if (kb) __syncthreads();
        for (int i = tid; i < KC * 128 / 4; i += 256)
            ((float4*)w2s)[i] = ((const float4*)(W2 + kb * 128))[i];
        int ko = kb + kq * 4;
        float4 bv = *(const float4*)(b1 + ko);
        float4 cv = *(const float4*)(c1 + ko);
        float4 v2 = *(const float4*)(V2 + ko);
#pragma unroll
        for (int si = 0; si < 2; ++si) {
            int sp = sgb * 2 + si;
            int l = ls[sp], r = rs[sp];
            float4 ar = *(const float4*)(A + (long)r * 1024 + ko);
            float4 al = *(const float4*)(A + (long)l * 1024 + ko);
            float4 bl = *(const float4*)(B + (long)(l + 1) * 1024 + ko);
            float4 br = *(const float4*)(B + (long)(r + 1) * 1024 + ko);
            float4 hx;
            hx.x = fmaxf(ar.x - al.x + bl.x - br.x + bv.x, 0.f);
            hx.y = fmaxf(ar.y - al.y + bl.y - br.y + bv.y, 0.f);
            hx.z = fmaxf(ar.z - al.z + bl.z - br.z + bv.z, 0.f);
            hx.w = fmaxf(ar.w - al.w + bl.w - br.w + bv.w, 0.f);
            *(float4*)&hid[sp][kq * 4] = hx;
            float4 vr = *(const float4*)(AV + (long)r * 1024 + ko);
            float4 vl = *(const float4*)(AV + (long)l * 1024 + ko);
            float4 ul = *(const float4*)(BV + (long)(l + 1) * 1024 + ko);
            float4 ur = *(const float4*)(BV + (long)(r + 1) * 1024 + ko);
            float h0 = fmaxf(vr.x - vl.x + ul.x - ur.x + cv.x, 0.f);
            float h1 = fmaxf(vr.y - vl.y + ul.y - ur.y + cv.y, 0.f);
            float h2 = fmaxf(vr.z - vl.z + ul.z - ur.z + cv.z, 0.f);
            float h3 = fmaxf(vr.w - vl.w + ul.w - ur.w + cv.w, 0.f);
            vacc[si] += h0 * v2.x + h1 * v2.y + h2 * v2.z + h3 * v2.w;
        }
        __syncthreads();
#pragma unroll 2
        for (int k = 0; k < KC; k += 4) {
            float4 h4[8];
#pragma unroll
            for (int j2 = 0; j2 < 8; ++j2)
                h4[j2] = *(const float4*)&hid[sgm * 8 + j2][k];
#pragma unroll
            for (int kk = 0; kk < 4; ++kk) {
                float4 wv = *(const float4*)&w2s[(k + kk) * 128 + chg * 4];
#pragma unroll
                for (int j2 = 0; j2 < 8; ++j2) {
                    float hx = (&h4[j2].x)[kk];
                    acc[j2][0] += hx * wv.x; acc[j2][1] += hx * wv.y;
                    acc[j2][2] += hx * wv.z; acc[j2][3] += hx * wv.w;
                }
            }
        }
    }

    float4 b2v = *(const float4*)(b2 + chg * 4);
#pragma unroll
    for (int j2 = 0; j2 < 8; ++j2) {
        int s = wg * TS + sgm * 8 + j2;
        float* o = out + (long)s * 129 + chg * 4;
        o[0] = acc[j2][0] + b2v.x; o[1] = acc[j2][1] + b2v.y;
        o[2] = acc[j2][2] + b2v.z; o[3] = acc[j2][3] + b2v.w;
    }
    float c2v = c2[0];
#pragma unroll
    for (int si = 0; si < 2; ++si) {
        float v = vacc[si];
        v += __shfl_xor(v, 4, 8);
        v += __shfl_xor(v, 2, 8);
        v += __shfl_xor(v, 1, 8);
        if (kq == 0) out[(long)(wg * TS + sgb * 2 + si) * 129 + 128] = v + c2v;
    }
}

extern "C" void kernel_launch(void* const* d_in, const int* in_sizes, int n_in,
                              void* d_out, int out_size, void* d_ws, size_t ws_size,
                              hipStream_t stream) {
    const int* tag_ids  = (const int*)d_in[0];
    const int* word_ids = (const int*)d_in[1];
    const float* tag_emb  = (const float*)d_in[2];
    const float* word_emb = (const float*)d_in[3];
    const float* Wf_ih = (const float*)d_in[4];
    const float* Wf_hh = (const float*)d_in[5];
    const float* bf    = (const float*)d_in[6];
    const float* Wb_ih = (const float*)d_in[7];
    const float* Wb_hh = (const float*)d_in[8];
    const float* bb    = (const float*)d_in[9];
    const float* W1 = (const float*)d_in[10];
    const float* b1 = (const float*)d_in[11];
    const float* W2 = (const float*)d_in[12];
    const float* b2 = (const float*)d_in[13];
    const float* V1 = (const float*)d_in[14];
    const float* c1 = (const float*)d_in[15];
    const float* V2 = (const float*)d_in[16];
    const float* c2 = (const float*)d_in[17];

    float* ws = (float*)d_ws;
    float* x   = ws + 256;
    float* gxf = x + T_LEN * 512;
    float* gxb = gxf + T_LEN * 2048;
    float* fwd = gxb + T_LEN * 2048;
    float* bwd = fwd + T_LEN * 512;   // contiguous after fwd (poisoned together)
    float* A   = bwd + T_LEN * 512;
    float* B   = A + T_LEN * 1024;
    float* AV  = B + T_LEN * 1024;
    float* BV  = AV + T_LEN * 1024;

    k_poison<<<(2 * T_LEN * 512) / 256, 256, 0, stream>>>(fwd);
    k_embed<<<T_LEN, 128, 0, stream>>>(tag_ids, word_ids, tag_emb, word_emb, x);
    k_gx<<<dim3(32, 13, 2), 256, 0, stream>>>(x, Wf_ih, bf, Wb_ih, bb, gxf, gxb);
    k_scan<<<64, 320, 0, stream>>>(gxf, gxb, Wf_hh, Wb_hh, fwd, bwd);
    k_tables<<<dim3(16, 13, 4), 256, 0, stream>>>(fwd, bwd, W1, V1, A, B, AV, BV);
    k_span<<<NSPAN / 64, 256, 0, stream>>>(A, B, AV, BV, W2, b1, b2, V2, c1, c2,
                                           (float*)d_out);
}